// Round 9
// baseline (150.399 us; speedup 1.0000x reference)
//
#include <hip/hip_runtime.h>

// SoftDtwRkdDistance: B=32, T=96, D=128, f32 in, scalar f32 out.
// Split design:
//   K0 xn:   row squared-norms.
//   K1 csq2: TWO pairs (a,b0),(a,b0+1) per block sharing the staged A-panel
//            (k-loop LDS reads -25%). C' = (xn_a+xn_b-2*dot)*rg2 written
//            diag-major into LDS, then copied (contiguous) to global.
//   K2 dp:   one wave per problem; 8-deep register prefetch; phase-specialized
//            (B-cells dead for d<=63 and d>=129 -> compile-time skipped).
//   K3 reduce: means + smooth-L1.
// Fallback: if ws too small for the 38 MB C buffer, run the round-3 fused kernel.

constexpr int TT = 96;
constexpr int DD = 128;
constexpr int BB = 32;
constexpr int NP = BB * BB;               // 1024
constexpr int NPAIR = BB * (BB + 1) / 2;  // 528
constexpr int NPROB = 2 * NPAIR;          // 1056
constexpr int NGRP = 272;                 // sum over a of ceil((32-a)/2)
constexpr int CSZ = TT * TT;              // 9216 floats per problem
constexpr float FINF = 1e10f;
constexpr float LOG2E = 1.4426950408889634f;
constexpr float LN2 = 0.6931471805599453f;

__device__ __forceinline__ int tri_base(int a) {   // pairs with first index < a
  return a * BB - (a * (a - 1)) / 2;
}
__device__ __forceinline__ void tri_decode(int pr, int& a, int& b) {
  a = (int)((65.0f - sqrtf(4225.0f - 8.0f * (float)pr)) * 0.5f);
  while (tri_base(a + 1) <= pr) ++a;
  while (tri_base(a) > pr) --a;
  b = a + (pr - tri_base(a));
}
__device__ __forceinline__ int diag_base(int d) {
  return (d <= 95) ? ((d * (d + 1)) >> 1)
                   : 4656 + (((d - 96) * (287 - d)) >> 1);
}
// softmin in z''-domain, op order matches reference (up, left, diag)
__device__ __forceinline__ float smin2(float u, float lf, float dg) {
  float m = fmaxf(fmaxf(u, lf), dg);
  float s = __builtin_amdgcn_exp2f(u - m) + __builtin_amdgcn_exp2f(lf - m)
          + __builtin_amdgcn_exp2f(dg - m);
  return m + __builtin_amdgcn_logf(s);
}

// K0: row squared-norms xn[2][BB*TT]
__global__ void xn_kernel(const float* __restrict__ xs,
                          const float* __restrict__ xt,
                          float* __restrict__ xn) {
  int idx = blockIdx.x * 256 + threadIdx.x;
  if (idx >= 2 * BB * TT) return;
  int which = idx / (BB * TT);
  int row = idx - which * (BB * TT);
  const float* x = which ? xt : xs;
  const float4* xv = reinterpret_cast<const float4*>(x + (size_t)row * DD);
  float acc = 0.f;
#pragma unroll
  for (int k = 0; k < DD / 4; ++k) {
    float4 v = xv[k];
    acc = fmaf(v.x, v.x, acc);
    acc = fmaf(v.y, v.y, acc);
    acc = fmaf(v.z, v.z, acc);
    acc = fmaf(v.w, v.w, acc);
  }
  xn[idx] = acc;
}

// K1: two pairs per block, shared A panel. One 256-thread block per (group, tensor).
__global__ __launch_bounds__(256)
void csq_kernel(const float* __restrict__ xs,
                const float* __restrict__ xt,
                const float* __restrict__ xn,
                const float* __restrict__ gptr,
                float* __restrict__ Cd) {
  // staging: A,B0,B1 panels [96][36] floats = 10368 floats; Cs (9216) aliases.
  __shared__ __align__(16) float BUF[3 * TT * 36];
  __shared__ float xna[TT];
  __shared__ float xnb0[TT];
  __shared__ float xnb1[TT];

  // decode group -> (a, b0, b1)
  int g = blockIdx.x, a = 0;
  for (;;) { int cnt = (BB - a + 1) >> 1; if (g < cnt) break; g -= cnt; ++a; }
  const int b0 = a + 2 * g;
  const int b1 = (b0 + 1 < BB) ? b0 + 1 : b0;

  const int w = blockIdx.y;
  const float* x = w ? xt : xs;
  const float* xnw = xn + w * (BB * TT);
  const float* xa  = x + (size_t)a  * TT * DD;
  const float* xb0 = x + (size_t)b0 * TT * DD;
  const float* xb1 = x + (size_t)b1 * TT * DD;
  const int tid = threadIdx.x;

  if (tid < TT) {
    xna[tid]  = xnw[a  * TT + tid];
    xnb0[tid] = xnw[b0 * TT + tid];
    xnb1[tid] = xnw[b1 * TT + tid];
  }

  // lane remap: each wave spans 8 tx x 2 ty -> LDS reads <=2-way
  const int wv = tid >> 6;
  const int lane = tid & 63;
  const int tx = (lane & 7) + (wv & 1) * 8;      // 0..15
  const int ty = (lane >> 3) + (wv >> 1) * 8;    // 0..15
  const int t0 = ty * 6, s0 = tx * 6;

  float acc0[6][6], acc1[6][6];
#pragma unroll
  for (int r = 0; r < 6; ++r)
#pragma unroll
    for (int c = 0; c < 6; ++c) { acc0[r][c] = 0.f; acc1[r][c] = 0.f; }

  for (int d0 = 0; d0 < DD; d0 += 32) {
    __syncthreads();   // previous chunk's reads done before overwrite
    const float4* ga  = reinterpret_cast<const float4*>(xa  + d0);
    const float4* gb0 = reinterpret_cast<const float4*>(xb0 + d0);
    const float4* gb1 = reinterpret_cast<const float4*>(xb1 + d0);
    float4* s4 = reinterpret_cast<float4*>(BUF);
#pragma unroll
    for (int it = 0; it < 3; ++it) {
      int idx = tid + it * 256;          // 0..767
      int t = idx >> 3, k4 = idx & 7;    // row 0..95, float4 0..7
      s4[t * 9 + k4]        = ga [t * 32 + k4];
      s4[864 + t * 9 + k4]  = gb0[t * 32 + k4];
      s4[1728 + t * 9 + k4] = gb1[t * 32 + k4];
    }
    __syncthreads();
    const float4* B4 = reinterpret_cast<const float4*>(BUF);
#pragma unroll
    for (int k4 = 0; k4 < 8; ++k4) {
      float4 av[6], bv[6];
#pragma unroll
      for (int r = 0; r < 6; ++r) av[r] = B4[(t0 + r) * 9 + k4];
#pragma unroll
      for (int c = 0; c < 6; ++c) bv[c] = B4[864 + (s0 + c) * 9 + k4];
#pragma unroll
      for (int r = 0; r < 6; ++r)
#pragma unroll
        for (int c = 0; c < 6; ++c) {
          acc0[r][c] = fmaf(av[r].x, bv[c].x, acc0[r][c]);
          acc0[r][c] = fmaf(av[r].y, bv[c].y, acc0[r][c]);
          acc0[r][c] = fmaf(av[r].z, bv[c].z, acc0[r][c]);
          acc0[r][c] = fmaf(av[r].w, bv[c].w, acc0[r][c]);
        }
#pragma unroll
      for (int c = 0; c < 6; ++c) bv[c] = B4[1728 + (s0 + c) * 9 + k4];
#pragma unroll
      for (int r = 0; r < 6; ++r)
#pragma unroll
        for (int c = 0; c < 6; ++c) {
          acc1[r][c] = fmaf(av[r].x, bv[c].x, acc1[r][c]);
          acc1[r][c] = fmaf(av[r].y, bv[c].y, acc1[r][c]);
          acc1[r][c] = fmaf(av[r].z, bv[c].z, acc1[r][c]);
          acc1[r][c] = fmaf(av[r].w, bv[c].w, acc1[r][c]);
        }
    }
  }

  const float rg2 = -LOG2E / gptr[0];
  float* Cs = BUF;                      // alias staging (dead after barrier)
  const int pr0 = tri_base(a) + (b0 - a);

  // ---- pair 0: diag-major writeback to LDS, then contiguous copy-out ----
  __syncthreads();
#pragma unroll
  for (int r = 0; r < 6; ++r) {
    const int i = t0 + r;
    float xr = xna[i];
#pragma unroll
    for (int c = 0; c < 6; ++c) {
      const int j = s0 + c;
      float cv = xr + xnb0[j] - 2.0f * acc0[r][c];   // exact ref C
      const int d = i + j;
      const int pos = (d <= 95) ? i : i - (d - 95);
      Cs[diag_base(d) + pos] = cv * rg2;
    }
  }
  __syncthreads();
  {
    const size_t qb = (size_t)(w * NPAIR + pr0) * CSZ;
    for (int d = wv; d < 2 * TT - 1; d += 4) {
      int len = d <= 95 ? d + 1 : 191 - d;
      int base = diag_base(d);
      if (lane < len)                 Cd[qb + base + lane]      = Cs[base + lane];
      if (len > 64 && lane < len - 64) Cd[qb + base + 64 + lane] = Cs[base + 64 + lane];
    }
  }

  // ---- pair 1 (skip when duplicate tail) ----
  if (b1 > b0) {
    __syncthreads();
#pragma unroll
    for (int r = 0; r < 6; ++r) {
      const int i = t0 + r;
      float xr = xna[i];
#pragma unroll
      for (int c = 0; c < 6; ++c) {
        const int j = s0 + c;
        float cv = xr + xnb1[j] - 2.0f * acc1[r][c];
        const int d = i + j;
        const int pos = (d <= 95) ? i : i - (d - 95);
        Cs[diag_base(d) + pos] = cv * rg2;
      }
    }
    __syncthreads();
    const size_t qb = (size_t)(w * NPAIR + pr0 + 1) * CSZ;
    for (int d = wv; d < 2 * TT - 1; d += 4) {
      int len = d <= 95 ? d + 1 : 191 - d;
      int base = diag_base(d);
      if (lane < len)                 Cd[qb + base + lane]      = Cs[base + lane];
      if (len > 64 && lane < len - 64) Cd[qb + base + 64 + lane] = Cs[base + 64 + lane];
    }
  }
}

// K2: DP. One wave per problem q = w*528 + pr. No LDS.
// 8-deep prefetch; B-side compile-time skipped where provably NEGI.
#define STEP_RISE(d, qa, qb) do {                                        \
    float cA = qa;                                                       \
    { int dn = (d) + 8;                                                  \
      if (dn <= 190) { int nb = diag_base(dn); qa = cb[nb + l]; }        \
      if (dn <= 190 && dn >= 64) { int nb = diag_base(dn); qb = cb[nb + 64 + l]; } } \
    float rA1 = __shfl(A1, lm1);                                         \
    float upA = l0 ? NEGI : rA1;                                         \
    float dgA = l0 ? NEGI : pA1;                                         \
    float nA = cA + smin2(upA, A1, dgA);                                 \
    if ((d) >= 64) {                                                     \
      float cB = qb;                                                     \
      float rB1 = __shfl(B1, lm1);                                       \
      float upB = l0 ? rA1 : rB1;                                        \
      float dgB = l0 ? pA1 : pB1;                                        \
      float nB = cB + smin2(upB, B1, dgB);                               \
      B2 = B1;                                                           \
      B1 = (64 + l < (d) + 1) ? nB : NEGI;                               \
      pB1 = rB1;                                                         \
    }                                                                    \
    A2 = A1;                                                             \
    A1 = (l < (d) + 1) ? nA : NEGI;                                      \
    pA1 = rA1;                                                           \
  } while (0)

#define STEP_FALL(d, qa, qb) do {                                        \
    float cA = qa;                                                       \
    { int dn = (d) + 8;                                                  \
      if (dn <= 190) { int nb = diag_base(dn); qa = cb[nb + l]; }        \
      if (dn <= 128) { int nb = diag_base(dn); qb = cb[nb + 64 + l]; } } \
    float rA1 = __shfl(A1, lp1);                                         \
    float rB1 = ((d) <= 128) ? __shfl(B1, lp1) : NEGI;                   \
    float lfA = l63 ? rB1 : rA1;                                         \
    float dgA = l63 ? pB1 : pA1;                                         \
    float nA = cA + smin2(A1, lfA, dgA);                                 \
    if ((d) <= 128) {                                                    \
      float cB = qb;                                                     \
      float nB = cB + smin2(B1, rB1, pB1);                               \
      B1 = (64 + l < 191 - (d)) ? nB : NEGI;                             \
      pB1 = rB1;                                                         \
    }                                                                    \
    A1 = (l < 191 - (d)) ? nA : NEGI;                                    \
    pA1 = rA1;                                                           \
  } while (0)

__global__ __launch_bounds__(64)
void dp_kernel(const float* __restrict__ Cd,
               const float* __restrict__ gptr,
               float* __restrict__ dtw) {
  const int q = blockIdx.x;
  const int l = threadIdx.x;
  const float gamma = gptr[0];
  const float rg2 = -LOG2E / gamma;
  const float NEGI = FINF * rg2;          // invalid cell in z''-domain
  const float* __restrict__ cb = Cd + (size_t)q * CSZ;
  const int lp1 = (l + 1) & 63, lm1 = (l + 63) & 63;
  const bool l0 = (l == 0), l63 = (l == 63);

  // prefetch queue: slot (d-1)&7; preload diagonals 1..8 (A only; B dead)
  float q0A, q0B, q1A, q1B, q2A, q2B, q3A, q3B;
  float q4A, q4B, q5A, q5B, q6A, q6B, q7A, q7B;
  q0B = q1B = q2B = q3B = q4B = q5B = q6B = q7B = NEGI;
  {
    int b1 = diag_base(1), b2 = diag_base(2), b3 = diag_base(3), b4 = diag_base(4);
    int b5 = diag_base(5), b6 = diag_base(6), b7 = diag_base(7), b8 = diag_base(8);
    q0A = cb[b1 + l]; q1A = cb[b2 + l]; q2A = cb[b3 + l]; q3A = cb[b4 + l];
    q4A = cb[b5 + l]; q5A = cb[b6 + l]; q6A = cb[b7 + l]; q7A = cb[b8 + l];
  }

  // d=0 peel: r(0,0)'' = C''(0,0)
  float A1 = l0 ? cb[0] : NEGI;
  float B1 = NEGI, A2 = NEGI, B2 = NEGI;
  float pA1 = NEGI, pB1 = NEGI;   // shadow: last iter's shfl(A1/B1)

  // rising: d = 1..88 in groups of 8, then peel 89..95
  for (int g = 0; g < 11; ++g) {
    int d = 1 + g * 8;
    switch (d) {     // force literal d for constant folding
      case 1:  STEP_RISE(1,q0A,q0B);  STEP_RISE(2,q1A,q1B);  STEP_RISE(3,q2A,q2B);  STEP_RISE(4,q3A,q3B);
               STEP_RISE(5,q4A,q4B);  STEP_RISE(6,q5A,q5B);  STEP_RISE(7,q6A,q6B);  STEP_RISE(8,q7A,q7B);  break;
      case 9:  STEP_RISE(9,q0A,q0B);  STEP_RISE(10,q1A,q1B); STEP_RISE(11,q2A,q2B); STEP_RISE(12,q3A,q3B);
               STEP_RISE(13,q4A,q4B); STEP_RISE(14,q5A,q5B); STEP_RISE(15,q6A,q6B); STEP_RISE(16,q7A,q7B); break;
      case 17: STEP_RISE(17,q0A,q0B); STEP_RISE(18,q1A,q1B); STEP_RISE(19,q2A,q2B); STEP_RISE(20,q3A,q3B);
               STEP_RISE(21,q4A,q4B); STEP_RISE(22,q5A,q5B); STEP_RISE(23,q6A,q6B); STEP_RISE(24,q7A,q7B); break;
      case 25: STEP_RISE(25,q0A,q0B); STEP_RISE(26,q1A,q1B); STEP_RISE(27,q2A,q2B); STEP_RISE(28,q3A,q3B);
               STEP_RISE(29,q4A,q4B); STEP_RISE(30,q5A,q5B); STEP_RISE(31,q6A,q6B); STEP_RISE(32,q7A,q7B); break;
      case 33: STEP_RISE(33,q0A,q0B); STEP_RISE(34,q1A,q1B); STEP_RISE(35,q2A,q2B); STEP_RISE(36,q3A,q3B);
               STEP_RISE(37,q4A,q4B); STEP_RISE(38,q5A,q5B); STEP_RISE(39,q6A,q6B); STEP_RISE(40,q7A,q7B); break;
      case 41: STEP_RISE(41,q0A,q0B); STEP_RISE(42,q1A,q1B); STEP_RISE(43,q2A,q2B); STEP_RISE(44,q3A,q3B);
               STEP_RISE(45,q4A,q4B); STEP_RISE(46,q5A,q5B); STEP_RISE(47,q6A,q6B); STEP_RISE(48,q7A,q7B); break;
      case 49: STEP_RISE(49,q0A,q0B); STEP_RISE(50,q1A,q1B); STEP_RISE(51,q2A,q2B); STEP_RISE(52,q3A,q3B);
               STEP_RISE(53,q4A,q4B); STEP_RISE(54,q5A,q5B); STEP_RISE(55,q6A,q6B); STEP_RISE(56,q7A,q7B); break;
      case 57: STEP_RISE(57,q0A,q0B); STEP_RISE(58,q1A,q1B); STEP_RISE(59,q2A,q2B); STEP_RISE(60,q3A,q3B);
               STEP_RISE(61,q4A,q4B); STEP_RISE(62,q5A,q5B); STEP_RISE(63,q6A,q6B); STEP_RISE(64,q7A,q7B); break;
      case 65: STEP_RISE(65,q0A,q0B); STEP_RISE(66,q1A,q1B); STEP_RISE(67,q2A,q2B); STEP_RISE(68,q3A,q3B);
               STEP_RISE(69,q4A,q4B); STEP_RISE(70,q5A,q5B); STEP_RISE(71,q6A,q6B); STEP_RISE(72,q7A,q7B); break;
      case 73: STEP_RISE(73,q0A,q0B); STEP_RISE(74,q1A,q1B); STEP_RISE(75,q2A,q2B); STEP_RISE(76,q3A,q3B);
               STEP_RISE(77,q4A,q4B); STEP_RISE(78,q5A,q5B); STEP_RISE(79,q6A,q6B); STEP_RISE(80,q7A,q7B); break;
      default: STEP_RISE(81,q0A,q0B); STEP_RISE(82,q1A,q1B); STEP_RISE(83,q2A,q2B); STEP_RISE(84,q3A,q3B);
               STEP_RISE(85,q4A,q4B); STEP_RISE(86,q5A,q5B); STEP_RISE(87,q6A,q6B); STEP_RISE(88,q7A,q7B); break;
    }
  }
  STEP_RISE(89, q0A, q0B);
  STEP_RISE(90, q1A, q1B);
  STEP_RISE(91, q2A, q2B);
  STEP_RISE(92, q3A, q3B);
  STEP_RISE(93, q4A, q4B);
  STEP_RISE(94, q5A, q5B);
  STEP_RISE(95, q6A, q6B);

  // d = 96 boundary: offsets (0, +1, 0); consumes q7, prefetches 104
  {
    float cA = q7A, cB = q7B;
    int nb = diag_base(104);
    q7A = cb[nb + l]; q7B = cb[nb + 64 + l];
    float rA1 = __shfl(A1, lp1), rB1 = __shfl(B1, lp1);
    float lfA = l63 ? rB1 : rA1;
    float lfB = rB1;
    float nA = cA + smin2(A1, lfA, A2);
    float nB = cB + smin2(B1, lfB, B2);
    A2 = A1; B2 = B1;
    A1 = (l < 95) ? nA : NEGI;          // len = 95
    B1 = (64 + l < 95) ? nB : NEGI;
    pA1 = rA1; pB1 = rB1;
  }

  // falling: d = 97..184 in groups of 8, then peel 185..190
  for (int g = 0; g < 11; ++g) {
    int d = 97 + g * 8;
    switch (d) {
      case 97:  STEP_FALL(97,q0A,q0B);  STEP_FALL(98,q1A,q1B);  STEP_FALL(99,q2A,q2B);  STEP_FALL(100,q3A,q3B);
                STEP_FALL(101,q4A,q4B); STEP_FALL(102,q5A,q5B); STEP_FALL(103,q6A,q6B); STEP_FALL(104,q7A,q7B); break;
      case 105: STEP_FALL(105,q0A,q0B); STEP_FALL(106,q1A,q1B); STEP_FALL(107,q2A,q2B); STEP_FALL(108,q3A,q3B);
                STEP_FALL(109,q4A,q4B); STEP_FALL(110,q5A,q5B); STEP_FALL(111,q6A,q6B); STEP_FALL(112,q7A,q7B); break;
      case 113: STEP_FALL(113,q0A,q0B); STEP_FALL(114,q1A,q1B); STEP_FALL(115,q2A,q2B); STEP_FALL(116,q3A,q3B);
                STEP_FALL(117,q4A,q4B); STEP_FALL(118,q5A,q5B); STEP_FALL(119,q6A,q6B); STEP_FALL(120,q7A,q7B); break;
      case 121: STEP_FALL(121,q0A,q0B); STEP_FALL(122,q1A,q1B); STEP_FALL(123,q2A,q2B); STEP_FALL(124,q3A,q3B);
                STEP_FALL(125,q4A,q4B); STEP_FALL(126,q5A,q5B); STEP_FALL(127,q6A,q6B); STEP_FALL(128,q7A,q7B); break;
      case 129: STEP_FALL(129,q0A,q0B); STEP_FALL(130,q1A,q1B); STEP_FALL(131,q2A,q2B); STEP_FALL(132,q3A,q3B);
                STEP_FALL(133,q4A,q4B); STEP_FALL(134,q5A,q5B); STEP_FALL(135,q6A,q6B); STEP_FALL(136,q7A,q7B); break;
      case 137: STEP_FALL(137,q0A,q0B); STEP_FALL(138,q1A,q1B); STEP_FALL(139,q2A,q2B); STEP_FALL(140,q3A,q3B);
                STEP_FALL(141,q4A,q4B); STEP_FALL(142,q5A,q5B); STEP_FALL(143,q6A,q6B); STEP_FALL(144,q7A,q7B); break;
      case 145: STEP_FALL(145,q0A,q0B); STEP_FALL(146,q1A,q1B); STEP_FALL(147,q2A,q2B); STEP_FALL(148,q3A,q3B);
                STEP_FALL(149,q4A,q4B); STEP_FALL(150,q5A,q5B); STEP_FALL(151,q6A,q6B); STEP_FALL(152,q7A,q7B); break;
      case 153: STEP_FALL(153,q0A,q0B); STEP_FALL(154,q1A,q1B); STEP_FALL(155,q2A,q2B); STEP_FALL(156,q3A,q3B);
                STEP_FALL(157,q4A,q4B); STEP_FALL(158,q5A,q5B); STEP_FALL(159,q6A,q6B); STEP_FALL(160,q7A,q7B); break;
      case 161: STEP_FALL(161,q0A,q0B); STEP_FALL(162,q1A,q1B); STEP_FALL(163,q2A,q2B); STEP_FALL(164,q3A,q3B);
                STEP_FALL(165,q4A,q4B); STEP_FALL(166,q5A,q5B); STEP_FALL(167,q6A,q6B); STEP_FALL(168,q7A,q7B); break;
      case 169: STEP_FALL(169,q0A,q0B); STEP_FALL(170,q1A,q1B); STEP_FALL(171,q2A,q2B); STEP_FALL(172,q3A,q3B);
                STEP_FALL(173,q4A,q4B); STEP_FALL(174,q5A,q5B); STEP_FALL(175,q6A,q6B); STEP_FALL(176,q7A,q7B); break;
      default:  STEP_FALL(177,q0A,q0B); STEP_FALL(178,q1A,q1B); STEP_FALL(179,q2A,q2B); STEP_FALL(180,q3A,q3B);
                STEP_FALL(181,q4A,q4B); STEP_FALL(182,q5A,q5B); STEP_FALL(183,q6A,q6B); STEP_FALL(184,q7A,q7B); break;
    }
  }
  STEP_FALL(185, q0A, q0B);
  STEP_FALL(186, q1A, q1B);
  STEP_FALL(187, q2A, q2B);
  STEP_FALL(188, q3A, q3B);
  STEP_FALL(189, q4A, q4B);
  STEP_FALL(190, q5A, q5B);

  // cell (95,95) = position 0 of diag 190 -> lane 0, A1
  if (l0) {
    int w = q >= NPAIR ? 1 : 0;
    int pr = q - w * NPAIR;
    int a, b;
    tri_decode(pr, a, b);
    float v = A1 * (-gamma * LN2);       // back to r-domain
    dtw[w * NP + a * BB + b] = v;
    dtw[w * NP + b * BB + a] = v;
  }
}

// ---------------- Fallback fused kernel (round-3, proven) ----------------
__global__ __launch_bounds__(256)
void sdtw_fused_kernel(const float* __restrict__ xs,
                       const float* __restrict__ xt,
                       const float* __restrict__ xn,
                       const float* __restrict__ gptr,
                       float* __restrict__ dtw) {
  __shared__ __align__(16) float Cs[TT * TT];
  __shared__ float xna[TT];
  __shared__ float xnb[TT];

  const int pr = blockIdx.x;
  int a, b;
  tri_decode(pr, a, b);
  const int w = blockIdx.y;
  const float* x = w ? xt : xs;
  const float* xnw = xn + w * (BB * TT);
  const float* xa = x + (size_t)a * TT * DD;
  const float* xb = x + (size_t)b * TT * DD;
  const int tid = threadIdx.x;

  if (tid < TT) {
    xna[tid] = xnw[a * TT + tid];
    xnb[tid] = xnw[b * TT + tid];
  }
  constexpr int SROW = 36;
  float* xa_s = Cs;
  float* xb_s = Cs + TT * SROW;
  const int wv = tid >> 6;
  const int lane = tid & 63;
  const int tx = (lane & 7) + (wv & 1) * 8;
  const int ty = (lane >> 3) + (wv >> 1) * 8;
  const int t0 = ty * 6, s0 = tx * 6;
  float acc[6][6];
#pragma unroll
  for (int r = 0; r < 6; ++r)
#pragma unroll
    for (int c = 0; c < 6; ++c) acc[r][c] = 0.f;
  for (int d0 = 0; d0 < DD; d0 += 32) {
    __syncthreads();
    const float4* ga = reinterpret_cast<const float4*>(xa + d0);
    const float4* gb = reinterpret_cast<const float4*>(xb + d0);
    float4* sa = reinterpret_cast<float4*>(xa_s);
    float4* sb = reinterpret_cast<float4*>(xb_s);
#pragma unroll
    for (int it = 0; it < 3; ++it) {
      int idx = tid + it * 256;
      int t = idx >> 3, k4 = idx & 7;
      sa[t * (SROW / 4) + k4] = ga[t * (DD / 4) + k4];
      sb[t * (SROW / 4) + k4] = gb[t * (DD / 4) + k4];
    }
    __syncthreads();
#pragma unroll
    for (int k4 = 0; k4 < 8; ++k4) {
      float4 av4[6], bv4[6];
#pragma unroll
      for (int r = 0; r < 6; ++r)
        av4[r] = reinterpret_cast<const float4*>(xa_s + (t0 + r) * SROW)[k4];
#pragma unroll
      for (int c = 0; c < 6; ++c)
        bv4[c] = reinterpret_cast<const float4*>(xb_s + (s0 + c) * SROW)[k4];
#pragma unroll
      for (int r = 0; r < 6; ++r)
#pragma unroll
        for (int c = 0; c < 6; ++c) {
          acc[r][c] = fmaf(av4[r].x, bv4[c].x, acc[r][c]);
          acc[r][c] = fmaf(av4[r].y, bv4[c].y, acc[r][c]);
          acc[r][c] = fmaf(av4[r].z, bv4[c].z, acc[r][c]);
          acc[r][c] = fmaf(av4[r].w, bv4[c].w, acc[r][c]);
        }
    }
  }
  __syncthreads();
#pragma unroll
  for (int r = 0; r < 6; ++r) {
    float xr = xna[t0 + r];
#pragma unroll
    for (int c = 0; c < 6; ++c)
      Cs[(t0 + r) * TT + (s0 + c)] = xr + xnb[s0 + c] - 2.0f * acc[r][c];
  }
  __syncthreads();
  if (tid >= 64) return;

  const float gamma = gptr[0];
  const float rg = -1.0f / gamma;
  const int lm1 = (lane + 63) & 63;
  float A1 = FINF, B1 = FINF, A2 = FINF, B2 = FINF;
  for (int d = 0; d < 2 * TT - 1; ++d) {
    int jA = d - lane;
    bool vA = (jA >= 0) && (jA < TT);
    float cA = Cs[vA ? lane * TT + jA : 0];
    int iB = 64 + lane;
    int jB = d - iB;
    bool vB = (lane < 32) && (jB >= 0) && (jB < TT);
    float cB = Cs[vB ? iB * TT + jB : 0];
    float rA1 = __shfl(A1, lm1);
    float rB1 = __shfl(B1, lm1);
    float rA2 = __shfl(A2, lm1);
    float rB2 = __shfl(B2, lm1);
    const bool l0 = (lane == 0);
    float upA = l0 ? FINF : rA1;
    float dgA = l0 ? FINF : rA2;
    float upB = l0 ? rA1 : rB1;
    float dgB = l0 ? rA2 : rB2;
    float z0 = upA * rg, z1 = A1 * rg, z2 = dgA * rg;
    float m = fmaxf(fmaxf(z0, z1), z2);
    float s = expf(z0 - m) + expf(z1 - m) + expf(z2 - m);
    float sminA = -gamma * (m + logf(s));
    if (d == 0) sminA = 0.f;
    float y0 = upB * rg, y1 = B1 * rg, y2 = dgB * rg;
    float mb = fmaxf(fmaxf(y0, y1), y2);
    float sb2 = expf(y0 - mb) + expf(y1 - mb) + expf(y2 - mb);
    float sminB = -gamma * (mb + logf(sb2));
    float nA = vA ? cA + sminA : FINF;
    float nB = vB ? cB + sminB : FINF;
    A2 = A1; B2 = B1; A1 = nA; B1 = nB;
  }
  if (lane == 31) {
    float v = B1;
    dtw[w * NP + a * BB + b] = v;
    dtw[w * NP + b * BB + a] = v;
  }
}

// K3: means + normalized smooth-L1 (single block).
__global__ void reduce_kernel(const float* __restrict__ dtw,
                              float* __restrict__ out) {
  __shared__ double sh[256];
  const int tid = threadIdx.x;
  double ss = 0, st = 0;
  for (int k = tid; k < NP; k += 256) {
    ss += (double)dtw[k];
    st += (double)dtw[NP + k];
  }
  sh[tid] = ss; __syncthreads();
  for (int o = 128; o > 0; o >>= 1) { if (tid < o) sh[tid] += sh[tid + o]; __syncthreads(); }
  double sum_s = sh[0]; __syncthreads();
  sh[tid] = st; __syncthreads();
  for (int o = 128; o > 0; o >>= 1) { if (tid < o) sh[tid] += sh[tid + o]; __syncthreads(); }
  double sum_t = sh[0]; __syncthreads();

  float mean_s = (float)(sum_s / NP);
  float mean_t = (float)(sum_t / NP);

  double acc = 0;
  for (int k = tid; k < NP; k += 256) {
    float pred = dtw[k] / mean_s;
    float targ = dtw[NP + k] / mean_t;
    float d = pred - targ;
    float ad = fabsf(d);
    float v = ad < 1.f ? 0.5f * d * d : ad - 0.5f;
    acc += (double)v;
  }
  sh[tid] = acc; __syncthreads();
  for (int o = 128; o > 0; o >>= 1) { if (tid < o) sh[tid] += sh[tid + o]; __syncthreads(); }
  if (tid == 0) out[0] = (float)(sh[0] / NP);
}

extern "C" void kernel_launch(void* const* d_in, const int* in_sizes, int n_in,
                              void* d_out, int out_size, void* d_ws, size_t ws_size,
                              hipStream_t stream) {
  const float* student = (const float*)d_in[0];
  const float* teacher = (const float*)d_in[1];
  const float* gamma   = (const float*)d_in[2];
  float* ws = (float*)d_ws;

  const size_t cd_floats = (size_t)NPROB * CSZ;              // 9,732,096
  const size_t need = (cd_floats + 2 * NP + 2 * BB * TT) * sizeof(float);

  if (ws_size >= need) {
    float* Cd  = ws;
    float* dtw = ws + cd_floats;
    float* xnb = dtw + 2 * NP;
    xn_kernel<<<24, 256, 0, stream>>>(student, teacher, xnb);
    csq_kernel<<<dim3(NGRP, 2), 256, 0, stream>>>(student, teacher, xnb, gamma, Cd);
    dp_kernel<<<NPROB, 64, 0, stream>>>(Cd, gamma, dtw);
    reduce_kernel<<<1, 256, 0, stream>>>(dtw, (float*)d_out);
  } else {
    float* dtw = ws;
    float* xnb = ws + 2 * NP;
    xn_kernel<<<24, 256, 0, stream>>>(student, teacher, xnb);
    sdtw_fused_kernel<<<dim3(NPAIR, 2), 256, 0, stream>>>(student, teacher, xnb, gamma, dtw);
    reduce_kernel<<<1, 256, 0, stream>>>(dtw, (float*)d_out);
  }
}

// Round 10
// 106.046 us; speedup vs baseline: 1.4182x; 1.4182x over previous
//
#include <hip/hip_runtime.h>

// SoftDtwRkdDistance: B=32, T=96, D=128, f32 in, scalar f32 out.
// Split design (proven components + targeted fixes):
//   K0 xn:  row squared-norms.
//   K1 csq: round-4 core + T14 async-STAGE (prefetch next chunk into regs
//           before the barrier; ds_write after) + diag-major LDS epilogue
//           with straight coalesced copy-out.
//   K2 dp:  one wave per problem; 4-deep register prefetch, 2 shfls/diag,
//           compact phase-split loops (B-side skipped where provably dead).
//   K3 reduce: means + smooth-L1.
// Fallback: if ws too small for the 38 MB C buffer, run the round-3 fused kernel.

constexpr int TT = 96;
constexpr int DD = 128;
constexpr int BB = 32;
constexpr int NP = BB * BB;               // 1024
constexpr int NPAIR = BB * (BB + 1) / 2;  // 528
constexpr int NPROB = 2 * NPAIR;          // 1056
constexpr int CSZ = TT * TT;              // 9216 floats per problem
constexpr float FINF = 1e10f;
constexpr float LOG2E = 1.4426950408889634f;
constexpr float LN2 = 0.6931471805599453f;

__device__ __forceinline__ int tri_base(int a) {   // pairs with first index < a
  return a * BB - (a * (a - 1)) / 2;
}
__device__ __forceinline__ void tri_decode(int pr, int& a, int& b) {
  a = (int)((65.0f - sqrtf(4225.0f - 8.0f * (float)pr)) * 0.5f);
  while (tri_base(a + 1) <= pr) ++a;
  while (tri_base(a) > pr) --a;
  b = a + (pr - tri_base(a));
}
__device__ __forceinline__ int diag_base(int d) {
  return (d <= 95) ? ((d * (d + 1)) >> 1)
                   : 4656 + (((d - 96) * (287 - d)) >> 1);
}
// softmin in z''-domain, op order matches reference (up, left, diag)
__device__ __forceinline__ float smin2(float u, float lf, float dg) {
  float m = fmaxf(fmaxf(u, lf), dg);
  float s = __builtin_amdgcn_exp2f(u - m) + __builtin_amdgcn_exp2f(lf - m)
          + __builtin_amdgcn_exp2f(dg - m);
  return m + __builtin_amdgcn_logf(s);
}

// K0: row squared-norms xn[2][BB*TT]
__global__ void xn_kernel(const float* __restrict__ xs,
                          const float* __restrict__ xt,
                          float* __restrict__ xn) {
  int idx = blockIdx.x * 256 + threadIdx.x;
  if (idx >= 2 * BB * TT) return;
  int which = idx / (BB * TT);
  int row = idx - which * (BB * TT);
  const float* x = which ? xt : xs;
  const float4* xv = reinterpret_cast<const float4*>(x + (size_t)row * DD);
  float acc = 0.f;
#pragma unroll
  for (int k = 0; k < DD / 4; ++k) {
    float4 v = xv[k];
    acc = fmaf(v.x, v.x, acc);
    acc = fmaf(v.y, v.y, acc);
    acc = fmaf(v.z, v.z, acc);
    acc = fmaf(v.w, v.w, acc);
  }
  xn[idx] = acc;
}

// K1: C' in diag-major global layout. One 256-thread block per (pair, tensor).
// r4 core + async-STAGE prefetch + diag-major epilogue.
__global__ __launch_bounds__(256)
void csq_kernel(const float* __restrict__ xs,
                const float* __restrict__ xt,
                const float* __restrict__ xn,
                const float* __restrict__ gptr,
                float* __restrict__ Cd) {
  __shared__ __align__(16) float Cs[CSZ];   // staging aliases front (6912 floats)
  __shared__ float xna[TT];
  __shared__ float xnb[TT];

  const int pr = blockIdx.x;
  int a, b;
  tri_decode(pr, a, b);
  const int w = blockIdx.y;
  const float* x = w ? xt : xs;
  const float* xnw = xn + w * (BB * TT);
  const float* xa = x + (size_t)a * TT * DD;
  const float* xb = x + (size_t)b * TT * DD;
  const int tid = threadIdx.x;

  if (tid < TT) {
    xna[tid] = xnw[a * TT + tid];
    xnb[tid] = xnw[b * TT + tid];
  }

  constexpr int SROW = 36;                 // staged row stride (floats), 16B-aligned
  float* xa_s = Cs;                        // [96][36]
  float* xb_s = Cs + TT * SROW;

  // lane remap: each wave spans 8 tx x 2 ty -> av4/bv4 reads <=2-way
  const int wv = tid >> 6;
  const int lane = tid & 63;
  const int tx = (lane & 7) + (wv & 1) * 8;      // 0..15
  const int ty = (lane >> 3) + (wv >> 1) * 8;    // 0..15
  const int t0 = ty * 6, s0 = tx * 6;

  float acc[6][6];
#pragma unroll
  for (int r = 0; r < 6; ++r)
#pragma unroll
    for (int c = 0; c < 6; ++c) acc[r][c] = 0.f;

  const float4* ga = reinterpret_cast<const float4*>(xa);  // row stride 32 float4
  const float4* gb = reinterpret_cast<const float4*>(xb);
  float4* sa = reinterpret_cast<float4*>(xa_s);
  float4* sb = reinterpret_cast<float4*>(xb_s);

  // T14 async-STAGE: preload chunk 0 into registers
  float4 pa[3], pb[3];
#pragma unroll
  for (int it = 0; it < 3; ++it) {
    int idx = tid + it * 256, t = idx >> 3, k4 = idx & 7;
    pa[it] = ga[t * 32 + k4];
    pb[it] = gb[t * 32 + k4];
  }

  for (int c = 0; c < 4; ++c) {
    __syncthreads();   // previous chunk's reads done before overwrite
#pragma unroll
    for (int it = 0; it < 3; ++it) {
      int idx = tid + it * 256, t = idx >> 3, k4 = idx & 7;
      sa[t * (SROW / 4) + k4] = pa[it];
      sb[t * (SROW / 4) + k4] = pb[it];
    }
    if (c < 3) {       // issue next chunk's loads NOW; latency hides under k-loop
#pragma unroll
      for (int it = 0; it < 3; ++it) {
        int idx = tid + it * 256, t = idx >> 3, k4 = idx & 7;
        pa[it] = ga[t * 32 + (c + 1) * 8 + k4];
        pb[it] = gb[t * 32 + (c + 1) * 8 + k4];
      }
    }
    __syncthreads();
#pragma unroll
    for (int k4 = 0; k4 < 8; ++k4) {
      float4 av4[6], bv4[6];
#pragma unroll
      for (int r = 0; r < 6; ++r)
        av4[r] = reinterpret_cast<const float4*>(xa_s + (t0 + r) * SROW)[k4];
#pragma unroll
      for (int cc = 0; cc < 6; ++cc)
        bv4[cc] = reinterpret_cast<const float4*>(xb_s + (s0 + cc) * SROW)[k4];
#pragma unroll
      for (int r = 0; r < 6; ++r)
#pragma unroll
        for (int cc = 0; cc < 6; ++cc) {
          acc[r][cc] = fmaf(av4[r].x, bv4[cc].x, acc[r][cc]);
          acc[r][cc] = fmaf(av4[r].y, bv4[cc].y, acc[r][cc]);
          acc[r][cc] = fmaf(av4[r].z, bv4[cc].z, acc[r][cc]);
          acc[r][cc] = fmaf(av4[r].w, bv4[cc].w, acc[r][cc]);
        }
    }
  }

  // epilogue: diag-major write into LDS (r9-verified), then straight copy-out
  __syncthreads();   // all k-loop reads complete; safe to overwrite staging
  const float rg2 = -LOG2E / gptr[0];
#pragma unroll
  for (int r = 0; r < 6; ++r) {
    const int i = t0 + r;
    float xr = xna[i];
#pragma unroll
    for (int c = 0; c < 6; ++c) {
      const int j = s0 + c;
      float cv = xr + xnb[j] - 2.0f * acc[r][c];   // exact ref C
      const int d = i + j;
      const int pos = (d <= 95) ? i : i - (d - 95);
      Cs[diag_base(d) + pos] = cv * rg2;           // pre-scaled, diag-major
    }
  }
  __syncthreads();
  {
    float4* Cd4 = reinterpret_cast<float4*>(Cd + (size_t)(w * NPAIR + pr) * CSZ);
    const float4* Cs4 = reinterpret_cast<const float4*>(Cs);
#pragma unroll
    for (int it = 0; it < 9; ++it)     // 2304 float4s, fully coalesced
      Cd4[tid + it * 256] = Cs4[tid + it * 256];
  }
}

// K2: DP. One wave per problem q = w*528 + pr. No LDS.
// 4-deep prefetch (slot (d-1)&3), 2 shfls/diag via shadow regs,
// compact phase-split: B-side skipped where provably NEGI (r9-verified bounds).
#define ST_R(d, qa, qb) do {                                             \
    float cA = qa, cB = qb;                                              \
    { int dn = (d) + 4;                                                  \
      if (dn <= 190) { int nb = diag_base(dn);                           \
        qa = cb[nb + l]; qb = cb[nb + 64 + l]; } }                       \
    float rA1 = __shfl(A1, lm1), rB1 = __shfl(B1, lm1);                  \
    float upA = l0 ? NEGI : rA1;                                         \
    float dgA = l0 ? NEGI : pA1;                                         \
    float upB = l0 ? rA1 : rB1;                                          \
    float dgB = l0 ? pA1 : pB1;                                          \
    float nA = cA + smin2(upA, A1, dgA);                                 \
    float nB = cB + smin2(upB, B1, dgB);                                 \
    A2 = A1; B2 = B1;                                                    \
    A1 = (l < (d) + 1) ? nA : NEGI;                                      \
    B1 = (64 + l < (d) + 1) ? nB : NEGI;                                 \
    pA1 = rA1; pB1 = rB1;                                                \
  } while (0)

#define ST_RN(d, qa, qb) do {  /* rising, B provably dead (d<=63) */     \
    float cA = qa;                                                       \
    { int dn = (d) + 4;                                                  \
      if (dn <= 190) { int nb = diag_base(dn);                           \
        qa = cb[nb + l]; qb = cb[nb + 64 + l]; } }                       \
    float rA1 = __shfl(A1, lm1);                                         \
    float upA = l0 ? NEGI : rA1;                                         \
    float dgA = l0 ? NEGI : pA1;                                         \
    float nA = cA + smin2(upA, A1, dgA);                                 \
    A2 = A1;                                                             \
    A1 = (l < (d) + 1) ? nA : NEGI;                                      \
    pA1 = rA1;                                                           \
  } while (0)

#define ST_F(d, qa, qb) do {                                             \
    float cA = qa, cB = qb;                                              \
    { int dn = (d) + 4;                                                  \
      if (dn <= 190) { int nb = diag_base(dn); qa = cb[nb + l];          \
        if (dn <= 128) qb = cb[nb + 64 + l]; } }                         \
    float rA1 = __shfl(A1, lp1), rB1 = __shfl(B1, lp1);                  \
    float lfA = l63 ? rB1 : rA1;                                         \
    float dgA = l63 ? pB1 : pA1;                                         \
    float nA = cA + smin2(A1, lfA, dgA);                                 \
    float nB = cB + smin2(B1, rB1, pB1);                                 \
    A1 = (l < 191 - (d)) ? nA : NEGI;                                    \
    B1 = (64 + l < 191 - (d)) ? nB : NEGI;                               \
    pA1 = rA1; pB1 = rB1;                                                \
  } while (0)

#define ST_FN(d, qa, qb) do {  /* falling, B provably dead (d>=129) */   \
    float cA = qa;                                                       \
    { int dn = (d) + 4;                                                  \
      if (dn <= 190) { int nb = diag_base(dn); qa = cb[nb + l]; } }      \
    float rA1 = __shfl(A1, lp1);                                         \
    float lfA = l63 ? NEGI : rA1;                                        \
    float dgA = l63 ? NEGI : pA1;                                        \
    float nA = cA + smin2(A1, lfA, dgA);                                 \
    A1 = (l < 191 - (d)) ? nA : NEGI;                                    \
    pA1 = rA1;                                                           \
  } while (0)

__global__ __launch_bounds__(64)
void dp_kernel(const float* __restrict__ Cd,
               const float* __restrict__ gptr,
               float* __restrict__ dtw) {
  const int q = blockIdx.x;
  const int l = threadIdx.x;
  const float gamma = gptr[0];
  const float rg2 = -LOG2E / gamma;
  const float NEGI = FINF * rg2;          // invalid cell in z''-domain
  const float* __restrict__ cb = Cd + (size_t)q * CSZ;
  const int lp1 = (l + 1) & 63, lm1 = (l + 63) & 63;
  const bool l0 = (l == 0), l63 = (l == 63);

  // prefetch queue: slot (d-1)&3; preload diagonals 1..4
  float q0A, q0B, q1A, q1B, q2A, q2B, q3A, q3B;
  {
    int b1 = diag_base(1), b2 = diag_base(2), b3 = diag_base(3), b4 = diag_base(4);
    q0A = cb[b1 + l]; q0B = cb[b1 + 64 + l];
    q1A = cb[b2 + l]; q1B = cb[b2 + 64 + l];
    q2A = cb[b3 + l]; q2B = cb[b3 + 64 + l];
    q3A = cb[b4 + l]; q3B = cb[b4 + 64 + l];
  }

  // d=0 peel: r(0,0)'' = C''(0,0)
  float A1 = l0 ? cb[0] : NEGI;
  float B1 = NEGI, A2 = NEGI, B2 = NEGI;
  float pA1 = NEGI, pB1 = NEGI;   // shadow: last iter's shfl(A1/B1)

  // rising, B dead: d = 1..60 (15 groups), peel 61,62,63
  for (int g = 0; g < 15; ++g) {
    int d = 1 + g * 4;
    ST_RN(d,     q0A, q0B);
    ST_RN(d + 1, q1A, q1B);
    ST_RN(d + 2, q2A, q2B);
    ST_RN(d + 3, q3A, q3B);
  }
  ST_RN(61, q0A, q0B);
  ST_RN(62, q1A, q1B);
  ST_RN(63, q2A, q2B);

  // rising, full: d = 64, 65..92 (7 groups), peel 93,94,95
  ST_R(64, q3A, q3B);
  for (int g = 0; g < 7; ++g) {
    int d = 65 + g * 4;
    ST_R(d,     q0A, q0B);
    ST_R(d + 1, q1A, q1B);
    ST_R(d + 2, q2A, q2B);
    ST_R(d + 3, q3A, q3B);
  }
  ST_R(93, q0A, q0B);
  ST_R(94, q1A, q1B);
  ST_R(95, q2A, q2B);

  // d = 96 boundary: offsets (0, +1, 0); consumes q3, prefetches 100
  {
    float cA = q3A, cB = q3B;
    int nb = diag_base(100);
    q3A = cb[nb + l]; q3B = cb[nb + 64 + l];
    float rA1 = __shfl(A1, lp1), rB1 = __shfl(B1, lp1);
    float lfA = l63 ? rB1 : rA1;
    float lfB = rB1;
    float nA = cA + smin2(A1, lfA, A2);
    float nB = cB + smin2(B1, lfB, B2);
    A1 = (l < 95) ? nA : NEGI;          // len = 95
    B1 = (64 + l < 95) ? nB : NEGI;
    pA1 = rA1; pB1 = rB1;
  }

  // falling, full: d = 97..128 (8 groups)
  for (int g = 0; g < 8; ++g) {
    int d = 97 + g * 4;
    ST_F(d,     q0A, q0B);
    ST_F(d + 1, q1A, q1B);
    ST_F(d + 2, q2A, q2B);
    ST_F(d + 3, q3A, q3B);
  }
  // falling, B dead: d = 129..188 (15 groups), peel 189,190
  for (int g = 0; g < 15; ++g) {
    int d = 129 + g * 4;
    ST_FN(d,     q0A, q0B);
    ST_FN(d + 1, q1A, q1B);
    ST_FN(d + 2, q2A, q2B);
    ST_FN(d + 3, q3A, q3B);
  }
  ST_FN(189, q0A, q0B);
  ST_FN(190, q1A, q1B);

  // cell (95,95) = position 0 of diag 190 -> lane 0, A1
  if (l0) {
    int w = q >= NPAIR ? 1 : 0;
    int pr = q - w * NPAIR;
    int a, b;
    tri_decode(pr, a, b);
    float v = A1 * (-gamma * LN2);       // back to r-domain
    dtw[w * NP + a * BB + b] = v;
    dtw[w * NP + b * BB + a] = v;
  }
}

// ---------------- Fallback fused kernel (round-3, proven) ----------------
__global__ __launch_bounds__(256)
void sdtw_fused_kernel(const float* __restrict__ xs,
                       const float* __restrict__ xt,
                       const float* __restrict__ xn,
                       const float* __restrict__ gptr,
                       float* __restrict__ dtw) {
  __shared__ __align__(16) float Cs[TT * TT];
  __shared__ float xna[TT];
  __shared__ float xnb[TT];

  const int pr = blockIdx.x;
  int a, b;
  tri_decode(pr, a, b);
  const int w = blockIdx.y;
  const float* x = w ? xt : xs;
  const float* xnw = xn + w * (BB * TT);
  const float* xa = x + (size_t)a * TT * DD;
  const float* xb = x + (size_t)b * TT * DD;
  const int tid = threadIdx.x;

  if (tid < TT) {
    xna[tid] = xnw[a * TT + tid];
    xnb[tid] = xnw[b * TT + tid];
  }
  constexpr int SROW = 36;
  float* xa_s = Cs;
  float* xb_s = Cs + TT * SROW;
  const int wv = tid >> 6;
  const int lane = tid & 63;
  const int tx = (lane & 7) + (wv & 1) * 8;
  const int ty = (lane >> 3) + (wv >> 1) * 8;
  const int t0 = ty * 6, s0 = tx * 6;
  float acc[6][6];
#pragma unroll
  for (int r = 0; r < 6; ++r)
#pragma unroll
    for (int c = 0; c < 6; ++c) acc[r][c] = 0.f;
  for (int d0 = 0; d0 < DD; d0 += 32) {
    __syncthreads();
    const float4* ga = reinterpret_cast<const float4*>(xa + d0);
    const float4* gb = reinterpret_cast<const float4*>(xb + d0);
    float4* sa = reinterpret_cast<float4*>(xa_s);
    float4* sb = reinterpret_cast<float4*>(xb_s);
#pragma unroll
    for (int it = 0; it < 3; ++it) {
      int idx = tid + it * 256;
      int t = idx >> 3, k4 = idx & 7;
      sa[t * (SROW / 4) + k4] = ga[t * (DD / 4) + k4];
      sb[t * (SROW / 4) + k4] = gb[t * (DD / 4) + k4];
    }
    __syncthreads();
#pragma unroll
    for (int k4 = 0; k4 < 8; ++k4) {
      float4 av4[6], bv4[6];
#pragma unroll
      for (int r = 0; r < 6; ++r)
        av4[r] = reinterpret_cast<const float4*>(xa_s + (t0 + r) * SROW)[k4];
#pragma unroll
      for (int c = 0; c < 6; ++c)
        bv4[c] = reinterpret_cast<const float4*>(xb_s + (s0 + c) * SROW)[k4];
#pragma unroll
      for (int r = 0; r < 6; ++r)
#pragma unroll
        for (int c = 0; c < 6; ++c) {
          acc[r][c] = fmaf(av4[r].x, bv4[c].x, acc[r][c]);
          acc[r][c] = fmaf(av4[r].y, bv4[c].y, acc[r][c]);
          acc[r][c] = fmaf(av4[r].z, bv4[c].z, acc[r][c]);
          acc[r][c] = fmaf(av4[r].w, bv4[c].w, acc[r][c]);
        }
    }
  }
  __syncthreads();
#pragma unroll
  for (int r = 0; r < 6; ++r) {
    float xr = xna[t0 + r];
#pragma unroll
    for (int c = 0; c < 6; ++c)
      Cs[(t0 + r) * TT + (s0 + c)] = xr + xnb[s0 + c] - 2.0f * acc[r][c];
  }
  __syncthreads();
  if (tid >= 64) return;

  const float gamma = gptr[0];
  const float rg = -1.0f / gamma;
  const int lm1 = (lane + 63) & 63;
  float A1 = FINF, B1 = FINF, A2 = FINF, B2 = FINF;
  for (int d = 0; d < 2 * TT - 1; ++d) {
    int jA = d - lane;
    bool vA = (jA >= 0) && (jA < TT);
    float cA = Cs[vA ? lane * TT + jA : 0];
    int iB = 64 + lane;
    int jB = d - iB;
    bool vB = (lane < 32) && (jB >= 0) && (jB < TT);
    float cB = Cs[vB ? iB * TT + jB : 0];
    float rA1 = __shfl(A1, lm1);
    float rB1 = __shfl(B1, lm1);
    float rA2 = __shfl(A2, lm1);
    float rB2 = __shfl(B2, lm1);
    const bool l0 = (lane == 0);
    float upA = l0 ? FINF : rA1;
    float dgA = l0 ? FINF : rA2;
    float upB = l0 ? rA1 : rB1;
    float dgB = l0 ? rA2 : rB2;
    float z0 = upA * rg, z1 = A1 * rg, z2 = dgA * rg;
    float m = fmaxf(fmaxf(z0, z1), z2);
    float s = expf(z0 - m) + expf(z1 - m) + expf(z2 - m);
    float sminA = -gamma * (m + logf(s));
    if (d == 0) sminA = 0.f;
    float y0 = upB * rg, y1 = B1 * rg, y2 = dgB * rg;
    float mb = fmaxf(fmaxf(y0, y1), y2);
    float sb2 = expf(y0 - mb) + expf(y1 - mb) + expf(y2 - mb);
    float sminB = -gamma * (mb + logf(sb2));
    float nA = vA ? cA + sminA : FINF;
    float nB = vB ? cB + sminB : FINF;
    A2 = A1; B2 = B1; A1 = nA; B1 = nB;
  }
  if (lane == 31) {
    float v = B1;
    dtw[w * NP + a * BB + b] = v;
    dtw[w * NP + b * BB + a] = v;
  }
}

// K3: means + normalized smooth-L1 (single block).
__global__ void reduce_kernel(const float* __restrict__ dtw,
                              float* __restrict__ out) {
  __shared__ double sh[256];
  const int tid = threadIdx.x;
  double ss = 0, st = 0;
  for (int k = tid; k < NP; k += 256) {
    ss += (double)dtw[k];
    st += (double)dtw[NP + k];
  }
  sh[tid] = ss; __syncthreads();
  for (int o = 128; o > 0; o >>= 1) { if (tid < o) sh[tid] += sh[tid + o]; __syncthreads(); }
  double sum_s = sh[0]; __syncthreads();
  sh[tid] = st; __syncthreads();
  for (int o = 128; o > 0; o >>= 1) { if (tid < o) sh[tid] += sh[tid + o]; __syncthreads(); }
  double sum_t = sh[0]; __syncthreads();

  float mean_s = (float)(sum_s / NP);
  float mean_t = (float)(sum_t / NP);

  double acc = 0;
  for (int k = tid; k < NP; k += 256) {
    float pred = dtw[k] / mean_s;
    float targ = dtw[NP + k] / mean_t;
    float d = pred - targ;
    float ad = fabsf(d);
    float v = ad < 1.f ? 0.5f * d * d : ad - 0.5f;
    acc += (double)v;
  }
  sh[tid] = acc; __syncthreads();
  for (int o = 128; o > 0; o >>= 1) { if (tid < o) sh[tid] += sh[tid + o]; __syncthreads(); }
  if (tid == 0) out[0] = (float)(sh[0] / NP);
}

extern "C" void kernel_launch(void* const* d_in, const int* in_sizes, int n_in,
                              void* d_out, int out_size, void* d_ws, size_t ws_size,
                              hipStream_t stream) {
  const float* student = (const float*)d_in[0];
  const float* teacher = (const float*)d_in[1];
  const float* gamma   = (const float*)d_in[2];
  float* ws = (float*)d_ws;

  const size_t cd_floats = (size_t)NPROB * CSZ;              // 9,732,096
  const size_t need = (cd_floats + 2 * NP + 2 * BB * TT) * sizeof(float);

  if (ws_size >= need) {
    float* Cd  = ws;
    float* dtw = ws + cd_floats;
    float* xnb = dtw + 2 * NP;
    xn_kernel<<<24, 256, 0, stream>>>(student, teacher, xnb);
    csq_kernel<<<dim3(NPAIR, 2), 256, 0, stream>>>(student, teacher, xnb, gamma, Cd);
    dp_kernel<<<NPROB, 64, 0, stream>>>(Cd, gamma, dtw);
    reduce_kernel<<<1, 256, 0, stream>>>(dtw, (float*)d_out);
  } else {
    float* dtw = ws;
    float* xnb = ws + 2 * NP;
    xn_kernel<<<24, 256, 0, stream>>>(student, teacher, xnb);
    sdtw_fused_kernel<<<dim3(NPAIR, 2), 256, 0, stream>>>(student, teacher, xnb, gamma, dtw);
    reduce_kernel<<<1, 256, 0, stream>>>(dtw, (float*)d_out);
  }
}

// Round 11
// 92.881 us; speedup vs baseline: 1.6193x; 1.1417x over previous
//
#include <hip/hip_runtime.h>

// SoftDtwRkdDistance: B=32, T=96, D=128, f32 in, scalar f32 out.
// Split design:
//   K0 xn:  row squared-norms.
//   K1 csq: r7-proven core + per-row LDS slot rotation (store row t's k4
//           block at slot (k4+t/6)&7) -> conflict-free ds_read_b128
//           (bank group = (7*ty + r + k4) mod 8, all distinct).
//           C' = (xn_a+xn_b-2*dot)*rg2 in diag-major global layout.
//   K2 dp:  one wave per problem; 4-deep register prefetch, 2 shfls/diag,
//           compact phase-split loops (B-side skipped where provably dead).
//   K3 reduce: means + smooth-L1.
// Fallback: if ws too small for the 38 MB C buffer, run the round-3 fused kernel.

constexpr int TT = 96;
constexpr int DD = 128;
constexpr int BB = 32;
constexpr int NP = BB * BB;               // 1024
constexpr int NPAIR = BB * (BB + 1) / 2;  // 528
constexpr int NPROB = 2 * NPAIR;          // 1056
constexpr int CSZ = TT * TT;              // 9216 floats per problem
constexpr float FINF = 1e10f;
constexpr float LOG2E = 1.4426950408889634f;
constexpr float LN2 = 0.6931471805599453f;

__device__ __forceinline__ int tri_base(int a) {   // pairs with first index < a
  return a * BB - (a * (a - 1)) / 2;
}
__device__ __forceinline__ void tri_decode(int pr, int& a, int& b) {
  a = (int)((65.0f - sqrtf(4225.0f - 8.0f * (float)pr)) * 0.5f);
  while (tri_base(a + 1) <= pr) ++a;
  while (tri_base(a) > pr) --a;
  b = a + (pr - tri_base(a));
}
__device__ __forceinline__ int diag_base(int d) {
  return (d <= 95) ? ((d * (d + 1)) >> 1)
                   : 4656 + (((d - 96) * (287 - d)) >> 1);
}
// softmin in z''-domain, op order matches reference (up, left, diag)
__device__ __forceinline__ float smin2(float u, float lf, float dg) {
  float m = fmaxf(fmaxf(u, lf), dg);
  float s = __builtin_amdgcn_exp2f(u - m) + __builtin_amdgcn_exp2f(lf - m)
          + __builtin_amdgcn_exp2f(dg - m);
  return m + __builtin_amdgcn_logf(s);
}

// K0: row squared-norms xn[2][BB*TT]
__global__ void xn_kernel(const float* __restrict__ xs,
                          const float* __restrict__ xt,
                          float* __restrict__ xn) {
  int idx = blockIdx.x * 256 + threadIdx.x;
  if (idx >= 2 * BB * TT) return;
  int which = idx / (BB * TT);
  int row = idx - which * (BB * TT);
  const float* x = which ? xt : xs;
  const float4* xv = reinterpret_cast<const float4*>(x + (size_t)row * DD);
  float acc = 0.f;
#pragma unroll
  for (int k = 0; k < DD / 4; ++k) {
    float4 v = xv[k];
    acc = fmaf(v.x, v.x, acc);
    acc = fmaf(v.y, v.y, acc);
    acc = fmaf(v.z, v.z, acc);
    acc = fmaf(v.w, v.w, acc);
  }
  xn[idx] = acc;
}

// K1: C' in diag-major global layout. One 256-thread block per (pair, tensor).
// r7 core + per-row slot-rotated LDS layout (conflict-free reads).
__global__ __launch_bounds__(256)
void csq_kernel(const float* __restrict__ xs,
                const float* __restrict__ xt,
                const float* __restrict__ xn,
                const float* __restrict__ gptr,
                float* __restrict__ Cd) {
  __shared__ __align__(16) float Cs[CSZ];   // staging aliases front (6912 floats)
  __shared__ float xna[TT];
  __shared__ float xnb[TT];

  const int pr = blockIdx.x;
  int a, b;
  tri_decode(pr, a, b);
  const int w = blockIdx.y;
  const float* x = w ? xt : xs;
  const float* xnw = xn + w * (BB * TT);
  const float* xa = x + (size_t)a * TT * DD;
  const float* xb = x + (size_t)b * TT * DD;
  const int tid = threadIdx.x;

  if (tid < TT) {
    xna[tid] = xnw[a * TT + tid];
    xnb[tid] = xnw[b * TT + tid];
  }

  // staged panels: [96 rows][9 float4 slots]; row t's logical k4 block lives
  // at slot (k4 + t/6) & 7 (slot 8 unused pad).
  float4* sa = reinterpret_cast<float4*>(Cs);          // A panel: 864 float4
  float4* sb = sa + TT * 9;                            // B panel: 864 float4

  // lane remap: tx/ty per r7
  const int wv = tid >> 6;
  const int lane = tid & 63;
  const int tx = (lane & 7) + (wv & 1) * 8;      // 0..15
  const int ty = (lane >> 3) + (wv >> 1) * 8;    // 0..15
  const int t0 = ty * 6, s0 = tx * 6;

  float acc[6][6];
#pragma unroll
  for (int r = 0; r < 6; ++r)
#pragma unroll
    for (int c = 0; c < 6; ++c) acc[r][c] = 0.f;

  const float4* ga = reinterpret_cast<const float4*>(xa);  // row stride 32
  const float4* gb = reinterpret_cast<const float4*>(xb);

  for (int d0 = 0; d0 < 4; ++d0) {     // 4 chunks of 8 float4 (32 k)
    __syncthreads();   // previous chunk's reads done before overwrite
#pragma unroll
    for (int it = 0; it < 3; ++it) {
      int idx = tid + it * 256;        // 0..767
      int t = idx >> 3, k4 = idx & 7;  // row, logical slot
      int slot = (k4 + (t / 6)) & 7;   // rotated storage slot
      sa[t * 9 + slot] = ga[t * 32 + d0 * 8 + k4];
      sb[t * 9 + slot] = gb[t * 32 + d0 * 8 + k4];
    }
    __syncthreads();
#pragma unroll
    for (int k4 = 0; k4 < 8; ++k4) {
      float4 av4[6], bv4[6];
      const int sA = (k4 + ty) & 7;    // rotated slot for this lane's A rows
      const int sB = (k4 + tx) & 7;    // rotated slot for this lane's B rows
#pragma unroll
      for (int r = 0; r < 6; ++r)
        av4[r] = sa[(t0 + r) * 9 + sA];
#pragma unroll
      for (int c = 0; c < 6; ++c)
        bv4[c] = sb[(s0 + c) * 9 + sB];
#pragma unroll
      for (int r = 0; r < 6; ++r)
#pragma unroll
        for (int c = 0; c < 6; ++c) {
          acc[r][c] = fmaf(av4[r].x, bv4[c].x, acc[r][c]);
          acc[r][c] = fmaf(av4[r].y, bv4[c].y, acc[r][c]);
          acc[r][c] = fmaf(av4[r].z, bv4[c].z, acc[r][c]);
          acc[r][c] = fmaf(av4[r].w, bv4[c].w, acc[r][c]);
        }
    }
  }
  __syncthreads();
  const float rg2 = -LOG2E / gptr[0];
#pragma unroll
  for (int r = 0; r < 6; ++r) {
    float xr = xna[t0 + r];
#pragma unroll
    for (int c = 0; c < 6; ++c) {
      float cv = xr + xnb[s0 + c] - 2.0f * acc[r][c];   // exact ref C
      Cs[(t0 + r) * TT + (s0 + c)] = cv * rg2;          // pre-scaled, row-major
    }
  }
  __syncthreads();

  // write-out: diag-major, coalesced; wave wv handles diagonals d ≡ wv (mod 4)
  const size_t qb = (size_t)(w * NPAIR + pr) * CSZ;
  for (int d = wv; d < 2 * TT - 1; d += 4) {
    int s = d <= 95 ? 0 : d - 95;
    int len = d <= 95 ? d + 1 : 191 - d;
    int base = diag_base(d);
    if (lane < len) {
      int i = s + lane;
      Cd[qb + base + lane] = Cs[i * TT + (d - i)];
    }
    if (len > 64 && lane < len - 64) {
      int i = s + 64 + lane;
      Cd[qb + base + 64 + lane] = Cs[i * TT + (d - i)];
    }
  }
}

// K2: DP. One wave per problem q = w*528 + pr. No LDS.
// 4-deep prefetch (slot (d-1)&3), 2 shfls/diag via shadow regs,
// compact phase-split: B-side skipped where provably NEGI.
#define ST_R(d, qa, qb) do {                                             \
    float cA = qa, cB = qb;                                              \
    { int dn = (d) + 4;                                                  \
      if (dn <= 190) { int nb = diag_base(dn);                           \
        qa = cb[nb + l]; qb = cb[nb + 64 + l]; } }                       \
    float rA1 = __shfl(A1, lm1), rB1 = __shfl(B1, lm1);                  \
    float upA = l0 ? NEGI : rA1;                                         \
    float dgA = l0 ? NEGI : pA1;                                         \
    float upB = l0 ? rA1 : rB1;                                          \
    float dgB = l0 ? pA1 : pB1;                                          \
    float nA = cA + smin2(upA, A1, dgA);                                 \
    float nB = cB + smin2(upB, B1, dgB);                                 \
    A2 = A1; B2 = B1;                                                    \
    A1 = (l < (d) + 1) ? nA : NEGI;                                      \
    B1 = (64 + l < (d) + 1) ? nB : NEGI;                                 \
    pA1 = rA1; pB1 = rB1;                                                \
  } while (0)

#define ST_RN(d, qa, qb) do {  /* rising, B provably dead (d<=63) */     \
    float cA = qa;                                                       \
    { int dn = (d) + 4;                                                  \
      if (dn <= 190) { int nb = diag_base(dn);                           \
        qa = cb[nb + l]; qb = cb[nb + 64 + l]; } }                       \
    float rA1 = __shfl(A1, lm1);                                         \
    float upA = l0 ? NEGI : rA1;                                         \
    float dgA = l0 ? NEGI : pA1;                                         \
    float nA = cA + smin2(upA, A1, dgA);                                 \
    A2 = A1;                                                             \
    A1 = (l < (d) + 1) ? nA : NEGI;                                      \
    pA1 = rA1;                                                           \
  } while (0)

#define ST_F(d, qa, qb) do {                                             \
    float cA = qa, cB = qb;                                              \
    { int dn = (d) + 4;                                                  \
      if (dn <= 190) { int nb = diag_base(dn); qa = cb[nb + l];          \
        if (dn <= 128) qb = cb[nb + 64 + l]; } }                         \
    float rA1 = __shfl(A1, lp1), rB1 = __shfl(B1, lp1);                  \
    float lfA = l63 ? rB1 : rA1;                                         \
    float dgA = l63 ? pB1 : pA1;                                         \
    float nA = cA + smin2(A1, lfA, dgA);                                 \
    float nB = cB + smin2(B1, rB1, pB1);                                 \
    A1 = (l < 191 - (d)) ? nA : NEGI;                                    \
    B1 = (64 + l < 191 - (d)) ? nB : NEGI;                               \
    pA1 = rA1; pB1 = rB1;                                                \
  } while (0)

#define ST_FN(d, qa, qb) do {  /* falling, B provably dead (d>=129) */   \
    float cA = qa;                                                       \
    { int dn = (d) + 4;                                                  \
      if (dn <= 190) { int nb = diag_base(dn); qa = cb[nb + l]; } }      \
    float rA1 = __shfl(A1, lp1);                                         \
    float lfA = l63 ? NEGI : rA1;                                        \
    float dgA = l63 ? NEGI : pA1;                                        \
    float nA = cA + smin2(A1, lfA, dgA);                                 \
    A1 = (l < 191 - (d)) ? nA : NEGI;                                    \
    pA1 = rA1;                                                           \
  } while (0)

__global__ __launch_bounds__(64)
void dp_kernel(const float* __restrict__ Cd,
               const float* __restrict__ gptr,
               float* __restrict__ dtw) {
  const int q = blockIdx.x;
  const int l = threadIdx.x;
  const float gamma = gptr[0];
  const float rg2 = -LOG2E / gamma;
  const float NEGI = FINF * rg2;          // invalid cell in z''-domain
  const float* __restrict__ cb = Cd + (size_t)q * CSZ;
  const int lp1 = (l + 1) & 63, lm1 = (l + 63) & 63;
  const bool l0 = (l == 0), l63 = (l == 63);

  // prefetch queue: slot (d-1)&3; preload diagonals 1..4
  float q0A, q0B, q1A, q1B, q2A, q2B, q3A, q3B;
  {
    int b1 = diag_base(1), b2 = diag_base(2), b3 = diag_base(3), b4 = diag_base(4);
    q0A = cb[b1 + l]; q0B = cb[b1 + 64 + l];
    q1A = cb[b2 + l]; q1B = cb[b2 + 64 + l];
    q2A = cb[b3 + l]; q2B = cb[b3 + 64 + l];
    q3A = cb[b4 + l]; q3B = cb[b4 + 64 + l];
  }

  // d=0 peel: r(0,0)'' = C''(0,0)
  float A1 = l0 ? cb[0] : NEGI;
  float B1 = NEGI, A2 = NEGI, B2 = NEGI;
  float pA1 = NEGI, pB1 = NEGI;   // shadow: last iter's shfl(A1/B1)

  // rising, B dead: d = 1..60 (15 groups), peel 61,62,63
  for (int g = 0; g < 15; ++g) {
    int d = 1 + g * 4;
    ST_RN(d,     q0A, q0B);
    ST_RN(d + 1, q1A, q1B);
    ST_RN(d + 2, q2A, q2B);
    ST_RN(d + 3, q3A, q3B);
  }
  ST_RN(61, q0A, q0B);
  ST_RN(62, q1A, q1B);
  ST_RN(63, q2A, q2B);

  // rising, full: d = 64, 65..92 (7 groups), peel 93,94,95
  ST_R(64, q3A, q3B);
  for (int g = 0; g < 7; ++g) {
    int d = 65 + g * 4;
    ST_R(d,     q0A, q0B);
    ST_R(d + 1, q1A, q1B);
    ST_R(d + 2, q2A, q2B);
    ST_R(d + 3, q3A, q3B);
  }
  ST_R(93, q0A, q0B);
  ST_R(94, q1A, q1B);
  ST_R(95, q2A, q2B);

  // d = 96 boundary: offsets (0, +1, 0); consumes q3, prefetches 100
  {
    float cA = q3A, cB = q3B;
    int nb = diag_base(100);
    q3A = cb[nb + l]; q3B = cb[nb + 64 + l];
    float rA1 = __shfl(A1, lp1), rB1 = __shfl(B1, lp1);
    float lfA = l63 ? rB1 : rA1;
    float lfB = rB1;
    float nA = cA + smin2(A1, lfA, A2);
    float nB = cB + smin2(B1, lfB, B2);
    A1 = (l < 95) ? nA : NEGI;          // len = 95
    B1 = (64 + l < 95) ? nB : NEGI;
    pA1 = rA1; pB1 = rB1;
  }

  // falling, full: d = 97..128 (8 groups)
  for (int g = 0; g < 8; ++g) {
    int d = 97 + g * 4;
    ST_F(d,     q0A, q0B);
    ST_F(d + 1, q1A, q1B);
    ST_F(d + 2, q2A, q2B);
    ST_F(d + 3, q3A, q3B);
  }
  // falling, B dead: d = 129..188 (15 groups), peel 189,190
  for (int g = 0; g < 15; ++g) {
    int d = 129 + g * 4;
    ST_FN(d,     q0A, q0B);
    ST_FN(d + 1, q1A, q1B);
    ST_FN(d + 2, q2A, q2B);
    ST_FN(d + 3, q3A, q3B);
  }
  ST_FN(189, q0A, q0B);
  ST_FN(190, q1A, q1B);

  // cell (95,95) = position 0 of diag 190 -> lane 0, A1
  if (l0) {
    int w = q >= NPAIR ? 1 : 0;
    int pr = q - w * NPAIR;
    int a, b;
    tri_decode(pr, a, b);
    float v = A1 * (-gamma * LN2);       // back to r-domain
    dtw[w * NP + a * BB + b] = v;
    dtw[w * NP + b * BB + a] = v;
  }
}

// ---------------- Fallback fused kernel (round-3, proven) ----------------
__global__ __launch_bounds__(256)
void sdtw_fused_kernel(const float* __restrict__ xs,
                       const float* __restrict__ xt,
                       const float* __restrict__ xn,
                       const float* __restrict__ gptr,
                       float* __restrict__ dtw) {
  __shared__ __align__(16) float Cs[TT * TT];
  __shared__ float xna[TT];
  __shared__ float xnb[TT];

  const int pr = blockIdx.x;
  int a, b;
  tri_decode(pr, a, b);
  const int w = blockIdx.y;
  const float* x = w ? xt : xs;
  const float* xnw = xn + w * (BB * TT);
  const float* xa = x + (size_t)a * TT * DD;
  const float* xb = x + (size_t)b * TT * DD;
  const int tid = threadIdx.x;

  if (tid < TT) {
    xna[tid] = xnw[a * TT + tid];
    xnb[tid] = xnw[b * TT + tid];
  }
  constexpr int SROW = 36;
  float* xa_s = Cs;
  float* xb_s = Cs + TT * SROW;
  const int wv = tid >> 6;
  const int lane = tid & 63;
  const int tx = (lane & 7) + (wv & 1) * 8;
  const int ty = (lane >> 3) + (wv >> 1) * 8;
  const int t0 = ty * 6, s0 = tx * 6;
  float acc[6][6];
#pragma unroll
  for (int r = 0; r < 6; ++r)
#pragma unroll
    for (int c = 0; c < 6; ++c) acc[r][c] = 0.f;
  for (int d0 = 0; d0 < DD; d0 += 32) {
    __syncthreads();
    const float4* ga = reinterpret_cast<const float4*>(xa + d0);
    const float4* gb = reinterpret_cast<const float4*>(xb + d0);
    float4* sa = reinterpret_cast<float4*>(xa_s);
    float4* sb = reinterpret_cast<float4*>(xb_s);
#pragma unroll
    for (int it = 0; it < 3; ++it) {
      int idx = tid + it * 256;
      int t = idx >> 3, k4 = idx & 7;
      sa[t * (SROW / 4) + k4] = ga[t * (DD / 4) + k4];
      sb[t * (SROW / 4) + k4] = gb[t * (DD / 4) + k4];
    }
    __syncthreads();
#pragma unroll
    for (int k4 = 0; k4 < 8; ++k4) {
      float4 av4[6], bv4[6];
#pragma unroll
      for (int r = 0; r < 6; ++r)
        av4[r] = reinterpret_cast<const float4*>(xa_s + (t0 + r) * SROW)[k4];
#pragma unroll
      for (int c = 0; c < 6; ++c)
        bv4[c] = reinterpret_cast<const float4*>(xb_s + (s0 + c) * SROW)[k4];
#pragma unroll
      for (int r = 0; r < 6; ++r)
#pragma unroll
        for (int c = 0; c < 6; ++c) {
          acc[r][c] = fmaf(av4[r].x, bv4[c].x, acc[r][c]);
          acc[r][c] = fmaf(av4[r].y, bv4[c].y, acc[r][c]);
          acc[r][c] = fmaf(av4[r].z, bv4[c].z, acc[r][c]);
          acc[r][c] = fmaf(av4[r].w, bv4[c].w, acc[r][c]);
        }
    }
  }
  __syncthreads();
#pragma unroll
  for (int r = 0; r < 6; ++r) {
    float xr = xna[t0 + r];
#pragma unroll
    for (int c = 0; c < 6; ++c)
      Cs[(t0 + r) * TT + (s0 + c)] = xr + xnb[s0 + c] - 2.0f * acc[r][c];
  }
  __syncthreads();
  if (tid >= 64) return;

  const float gamma = gptr[0];
  const float rg = -1.0f / gamma;
  const int lm1 = (lane + 63) & 63;
  float A1 = FINF, B1 = FINF, A2 = FINF, B2 = FINF;
  for (int d = 0; d < 2 * TT - 1; ++d) {
    int jA = d - lane;
    bool vA = (jA >= 0) && (jA < TT);
    float cA = Cs[vA ? lane * TT + jA : 0];
    int iB = 64 + lane;
    int jB = d - iB;
    bool vB = (lane < 32) && (jB >= 0) && (jB < TT);
    float cB = Cs[vB ? iB * TT + jB : 0];
    float rA1 = __shfl(A1, lm1);
    float rB1 = __shfl(B1, lm1);
    float rA2 = __shfl(A2, lm1);
    float rB2 = __shfl(B2, lm1);
    const bool l0 = (lane == 0);
    float upA = l0 ? FINF : rA1;
    float dgA = l0 ? FINF : rA2;
    float upB = l0 ? rA1 : rB1;
    float dgB = l0 ? rA2 : rB2;
    float z0 = upA * rg, z1 = A1 * rg, z2 = dgA * rg;
    float m = fmaxf(fmaxf(z0, z1), z2);
    float s = expf(z0 - m) + expf(z1 - m) + expf(z2 - m);
    float sminA = -gamma * (m + logf(s));
    if (d == 0) sminA = 0.f;
    float y0 = upB * rg, y1 = B1 * rg, y2 = dgB * rg;
    float mb = fmaxf(fmaxf(y0, y1), y2);
    float sb2 = expf(y0 - mb) + expf(y1 - mb) + expf(y2 - mb);
    float sminB = -gamma * (mb + logf(sb2));
    float nA = vA ? cA + sminA : FINF;
    float nB = vB ? cB + sminB : FINF;
    A2 = A1; B2 = B1; A1 = nA; B1 = nB;
  }
  if (lane == 31) {
    float v = B1;
    dtw[w * NP + a * BB + b] = v;
    dtw[w * NP + b * BB + a] = v;
  }
}

// K3: means + normalized smooth-L1 (single block).
__global__ void reduce_kernel(const float* __restrict__ dtw,
                              float* __restrict__ out) {
  __shared__ double sh[256];
  const int tid = threadIdx.x;
  double ss = 0, st = 0;
  for (int k = tid; k < NP; k += 256) {
    ss += (double)dtw[k];
    st += (double)dtw[NP + k];
  }
  sh[tid] = ss; __syncthreads();
  for (int o = 128; o > 0; o >>= 1) { if (tid < o) sh[tid] += sh[tid + o]; __syncthreads(); }
  double sum_s = sh[0]; __syncthreads();
  sh[tid] = st; __syncthreads();
  for (int o = 128; o > 0; o >>= 1) { if (tid < o) sh[tid] += sh[tid + o]; __syncthreads(); }
  double sum_t = sh[0]; __syncthreads();

  float mean_s = (float)(sum_s / NP);
  float mean_t = (float)(sum_t / NP);

  double acc = 0;
  for (int k = tid; k < NP; k += 256) {
    float pred = dtw[k] / mean_s;
    float targ = dtw[NP + k] / mean_t;
    float d = pred - targ;
    float ad = fabsf(d);
    float v = ad < 1.f ? 0.5f * d * d : ad - 0.5f;
    acc += (double)v;
  }
  sh[tid] = acc; __syncthreads();
  for (int o = 128; o > 0; o >>= 1) { if (tid < o) sh[tid] += sh[tid + o]; __syncthreads(); }
  if (tid == 0) out[0] = (float)(sh[0] / NP);
}

extern "C" void kernel_launch(void* const* d_in, const int* in_sizes, int n_in,
                              void* d_out, int out_size, void* d_ws, size_t ws_size,
                              hipStream_t stream) {
  const float* student = (const float*)d_in[0];
  const float* teacher = (const float*)d_in[1];
  const float* gamma   = (const float*)d_in[2];
  float* ws = (float*)d_ws;

  const size_t cd_floats = (size_t)NPROB * CSZ;              // 9,732,096
  const size_t need = (cd_floats + 2 * NP + 2 * BB * TT) * sizeof(float);

  if (ws_size >= need) {
    float* Cd  = ws;
    float* dtw = ws + cd_floats;
    float* xnb = dtw + 2 * NP;
    xn_kernel<<<24, 256, 0, stream>>>(student, teacher, xnb);
    csq_kernel<<<dim3(NPAIR, 2), 256, 0, stream>>>(student, teacher, xnb, gamma, Cd);
    dp_kernel<<<NPROB, 64, 0, stream>>>(Cd, gamma, dtw);
    reduce_kernel<<<1, 256, 0, stream>>>(dtw, (float*)d_out);
  } else {
    float* dtw = ws;
    float* xnb = ws + 2 * NP;
    xn_kernel<<<24, 256, 0, stream>>>(student, teacher, xnb);
    sdtw_fused_kernel<<<dim3(NPAIR, 2), 256, 0, stream>>>(student, teacher, xnb, gamma, dtw);
    reduce_kernel<<<1, 256, 0, stream>>>(dtw, (float*)d_out);
  }
}